// Round 15
// baseline (35.735 us; speedup 1.0000x reference)
//
#include <hip/hip_runtime.h>
#include <stdint.h>

#define NB 2048
#define NCLASSES 80
#define CONF_T 0.05f
#define IOU_T 0.5f
#define MAX_DET 100
#define MAX_PER_CLASS 100

typedef unsigned long long u64;
typedef unsigned int u32;
typedef unsigned char u8;

__device__ __forceinline__ u64 shfl_xor_u64(u64 v, int mask) {
    int lo = (int)(u32)v, hi = (int)(u32)(v >> 32);
    lo = __shfl_xor(lo, mask, 64);
    hi = __shfl_xor(hi, mask, 64);
    return ((u64)(u32)hi << 32) | (u32)lo;
}

// 512-bucket monotone score hash (r14-validated): bits>>17 − 0x1E80.
__device__ __forceinline__ int sbucket(u32 bits) {
    int b = (int)(bits >> 17) - 0x1E80;
    return b < 0 ? 0 : (b > 511 ? 511 : b);
}

// ====================================================================
// Single dispatch, grid (B*10 + B) x 512:
//  blocks 0..B*10-1 : class role (r13/r14-validated): batch b=bid/10,
//                     wave w owns class (bid%10)*8+w; block-staged
//                     cls/score; pair-matrix NMS; supBytes[orig]
//                     exactly-once {0,1}; then ONE release fence +
//                     done[b]+=1 per block (r12-validated protocol,
//                     8x fewer fences, no redundant global scans).
//  blocks B*10..+B-1: select role (r14-validated histogram top-k):
//                     spin done[b]==10 -> acquire -> atomic-read
//                     supBytes -> histogram threshold -> candidates ->
//                     wave-0 256-reg-bitonic -> output.
// ====================================================================
__global__ __launch_bounds__(512) void nms_single(const float* __restrict__ pred,
                                                  u8* __restrict__ supBytes,
                                                  u32* __restrict__ done,
                                                  float* __restrict__ out, int B) {
    const int bid = blockIdx.x, tid = threadIdx.x;
    const int lane = tid & 63, wave = tid >> 6;            // 8 waves

    __shared__ __align__(16) char smem[49152];

    if (bid < B * 10) {
        // ==================== CLASS role ====================
        float2* csS  = (float2*)smem;                      // 16 KB
        u64*    wkey = (u64*)(smem + 16384);               // 4 KB  [8][64]
        float4* wb4  = (float4*)(smem + 20480);            // 8 KB  [8][64]
        u64*    wm   = (u64*)(smem + 28672);               // 4 KB  [8][64]
        u8*     fst  = (u8*)(smem + 32768);                // 16 KB [8][2048]

        const int b = bid / 10;
        const int c = (bid % 10) * 8 + wave;
        const float* P = pred + (size_t)b * NB * 6;
        u8* sb = supBytes + (size_t)b * NB;

        for (int i = tid; i < NB; i += 512)
            csS[i] = *reinterpret_cast<const float2*>(P + i * 6 + 4);
        __syncthreads();

        u64* wkeyW = wkey + wave * 64;
        float4* wb4W = wb4 + wave * 64;
        u64* wmW = wm + wave * 64;

        int cnt = 0;
        for (int base = 0; base < NB; base += 64) {
            int i = base + lane;
            float2 cs = csS[i];
            bool v = (cs.y > CONF_T) && ((int)cs.x == c);
            u64 m = __ballot(v);
            if (v) {
                int pos = cnt + __popcll(m & ((1ull << lane) - 1ull));
                if (pos < 64) {
                    float2 p01 = *reinterpret_cast<const float2*>(P + i * 6);
                    float2 p23 = *reinterpret_cast<const float2*>(P + i * 6 + 2);
                    wkeyW[pos] = ((u64)__float_as_uint(cs.y) << 32) | (u32)i;
                    wb4W[pos] = make_float4(p01.x, p01.y, p23.x, p23.y);
                }
            }
            cnt += __popcll(m);
        }
        __builtin_amdgcn_wave_barrier();

        if (cnt <= 64) {
            u64 mykey = 0ull; int orig = 0;
            float x1 = 0.f, y1 = 0.f, x2 = 0.f, y2 = 0.f, ar = 0.f;
            if (lane < cnt) {
                mykey = wkeyW[lane];
                orig = (int)(u32)mykey;
                float4 bx = wb4W[lane];
                x1 = bx.x; y1 = bx.y; x2 = bx.z; y2 = bx.w;
                ar = fmaxf(x2 - x1, 0.f) * fmaxf(y2 - y1, 0.f);
            }
            u64 mj = 0ull;
            if (lane < cnt) {
                for (int i = 0; i < cnt; ++i) {
                    u64 ki = wkeyW[i];
                    if (ki > mykey) {
                        float4 bi = wb4W[i];
                        float ari = fmaxf(bi.z - bi.x, 0.f) * fmaxf(bi.w - bi.y, 0.f);
                        float ix1 = fmaxf(bi.x, x1), iy1 = fmaxf(bi.y, y1);
                        float ix2 = fminf(bi.z, x2), iy2 = fminf(bi.w, y2);
                        float inter = fmaxf(ix2 - ix1, 0.f) * fmaxf(iy2 - iy1, 0.f);
                        float uni = ari + ar - inter;
                        if (inter / fmaxf(uni, 1e-8f) > IOU_T) mj |= 1ull << i;
                    }
                }
            }
            u64 conf = __ballot(mj != 0ull);
            bool sup = false;
            if (conf != 0ull) {                            // rare; wave-uniform
                u64 srcs = mj;
                #pragma unroll
                for (int d = 1; d < 64; d <<= 1) srcs |= shfl_xor_u64(srcs, d);
                wmW[lane] = mj;
                __builtin_amdgcn_wave_barrier();
                u64 Cset = srcs | conf;
                u64 keptS2 = 0ull, rem = Cset;
                while (rem) {
                    u64 t = rem, bestk = 0ull; int bi = -1;
                    while (t) {
                        int i = __ffsll(t) - 1; t &= t - 1;
                        u64 k = wkeyW[i];
                        if (k > bestk) { bestk = k; bi = i; }
                    }
                    rem &= ~(1ull << bi);
                    if ((wmW[bi] & keptS2) == 0ull) keptS2 |= 1ull << bi;
                }
                sup = (mj & keptS2) != 0ull;
            }
            if (lane < cnt) sb[orig] = sup ? 1 : 0;
        } else {
            // ---- exact LDS-rescan selection-greedy fallback (~never) ----
            volatile u8* vf = fst + wave * NB;
            for (int o = lane; o < NB; o += 64) vf[o] = 0;
            __builtin_amdgcn_wave_barrier();
            int keptCount = 0;
            for (;;) {
                u64 best = 0ull; int bo = -1;
                for (int o = lane; o < NB; o += 64) {
                    if (vf[o]) continue;
                    float2 cs = csS[o];
                    if (cs.y > CONF_T && (int)cs.x == c) {
                        u64 k = ((u64)__float_as_uint(cs.y) << 32) | (u32)o;
                        if (k > best) { best = k; bo = o; }
                    }
                }
                for (int d = 32; d >= 1; d >>= 1) {
                    u64 ob = shfl_xor_u64(best, d);
                    int obo = __shfl_xor(bo, d, 64);
                    if (ob > best) { best = ob; bo = obo; }
                }
                if (best == 0ull) break;
                keptCount++;
                int orig = (int)(u32)best;
                if (lane == 0) {
                    vf[orig] = 1;
                    sb[orig] = (keptCount > MAX_PER_CLASS) ? 1 : 0;
                }
                __builtin_amdgcn_wave_barrier();
                const float* q = P + orig * 6;
                float ax1 = q[0], ay1 = q[1], ax2 = q[2], ay2 = q[3];
                float aar = fmaxf(ax2 - ax1, 0.f) * fmaxf(ay2 - ay1, 0.f);
                for (int o = lane; o < NB; o += 64) {
                    if (vf[o]) continue;
                    float2 cs = csS[o];
                    if (cs.y > CONF_T && (int)cs.x == c) {
                        const float* q2 = P + o * 6;
                        float bx1 = q2[0], by1 = q2[1], bx2 = q2[2], by2 = q2[3];
                        float br = fmaxf(bx2 - bx1, 0.f) * fmaxf(by2 - by1, 0.f);
                        float ix1 = fmaxf(ax1, bx1), iy1 = fmaxf(ay1, by1);
                        float ix2 = fminf(ax2, bx2), iy2 = fminf(ay2, by2);
                        float inter = fmaxf(ix2 - ix1, 0.f) * fmaxf(iy2 - iy1, 0.f);
                        if (inter / fmaxf(aar + br - inter, 1e-8f) > IOU_T) {
                            vf[o] = 2;
                            sb[o] = 1;
                        }
                    }
                }
                __builtin_amdgcn_wave_barrier();
            }
        }

        // ---- release: all stores drained at barrier; one fence/block ----
        __syncthreads();
        if (tid == 0) { __threadfence(); atomicAdd(&done[b], 1u); }
    } else {
        // ==================== SELECT role ====================
        u32* smw  = (u32*)smem;                            // 2 KB
        int* hist = (int*)(smem + 2048);                   // 2 KB
        u64* cand = (u64*)(smem + 4096);                   // 2 KB
        u64* skey = (u64*)(smem + 8192);                   // 16 KB
        __shared__ int candCnt, TS, keptT;

        const int b = bid - B * 10;
        const float* P = pred + (size_t)b * NB * 6;

        for (int i = tid; i < 512; i += 512) hist[i] = 0;
        if (tid == 0) candCnt = 0;

        // ---- spin until all 10 class blocks of batch b signal ----
        if (tid == 0)
            while (atomicAdd(&done[b], 0u) < 10u)
                __builtin_amdgcn_s_sleep(8);
        __syncthreads();
        __threadfence();                                   // acquire
        {
            u32* sw = (u32*)(supBytes + (size_t)b * NB);
            for (int i = tid; i < NB / 4; i += 512)
                smw[i] = atomicOr(sw + i, 0u);             // r12-validated reads
        }
        __syncthreads();

        // ---- pass 1: keys in registers + histogram (r14, 4/thread) ----
        u64 kreg[4];
        #pragma unroll
        for (int t = 0; t < 4; ++t) {
            int i = tid + t * 512;
            float s = P[i * 6 + 5];
            bool sup = ((smw[i >> 2] >> ((i & 3) * 8)) & 0xFFu) != 0u;
            u64 kk = 0ull;
            if (s > CONF_T && !sup) {
                u32 bits = __float_as_uint(s);
                kk = ((u64)bits << 32) | (u32)i;
                atomicAdd(&hist[sbucket(bits)], 1);
            }
            kreg[t] = kk;
        }
        __syncthreads();

        // ---- threshold via wave-0 suffix scan (r14-validated) ----
        if (tid < 64) {
            int h[8], s = 0;
            #pragma unroll
            for (int t = 0; t < 8; ++t) { h[t] = hist[tid * 8 + t]; s += h[t]; }
            int v = s;
            #pragma unroll
            for (int d = 1; d < 64; d <<= 1) {
                int t2 = __shfl_down(v, d, 64);
                if (tid + d < 64) v += t2;
            }
            int total = __shfl(v, 0, 64);
            int target = total < MAX_DET ? total : MAX_DET;
            int run = v - s, bestB = -1;
            for (int t = 7; t >= 0; --t) {
                run += h[t];
                if (run >= target && bestB < 0) bestB = tid * 8 + t;
            }
            int T = bestB;
            #pragma unroll
            for (int d = 32; d >= 1; d >>= 1) {
                int o = __shfl_xor(T, d, 64);
                T = o > T ? o : T;
            }
            if (tid == 0) { TS = T; keptT = total; }
        }
        __syncthreads();

        // ---- gather candidates ----
        const int T = TS;
        #pragma unroll
        for (int t = 0; t < 4; ++t) {
            u64 kk = kreg[t];
            if (kk != 0ull && sbucket((u32)(kk >> 32)) >= T) {
                int pos = atomicAdd(&candCnt, 1);
                if (pos < 256) cand[pos] = kk;
            }
        }
        __syncthreads();

        int cc = candCnt;
        if (cc <= 256) {
            // ---- wave-0 register 256-bitonic, descending (r14) ----
            if (tid < 64) {
                const int ln = tid;
                const int iA = ln, iB = 64 + ln, iC = 128 + ln, iD = 192 + ln;
                u64 A  = (iA < cc) ? cand[iA] : 0ull;
                u64 Bv = (iB < cc) ? cand[iB] : 0ull;
                u64 C  = (iC < cc) ? cand[iC] : 0ull;
                u64 D  = (iD < cc) ? cand[iD] : 0ull;

                auto loc = [&](u64& X, u64& Y, int ix, int k) {
                    bool up = ((ix & k) == 0);
                    u64 mx = X > Y ? X : Y, mn = X > Y ? Y : X;
                    X = up ? mx : mn; Y = up ? mn : mx;
                };
                auto shf = [&](u64& V, int iv, int j, int k) {
                    u64 p = shfl_xor_u64(V, j);
                    bool low = ((ln & j) == 0);
                    bool up  = ((iv & k) == 0);
                    V = (low == up) ? (V > p ? V : p) : (V < p ? V : p);
                };
                for (int k = 2; k <= 256; k <<= 1) {
                    int jstart = k >> 1;
                    if (jstart >= 128) { loc(A, C, iA, k); loc(Bv, D, iB, k); }
                    if (jstart >= 64)  { loc(A, Bv, iA, k); loc(C, D, iC, k); }
                    for (int j = (jstart > 32 ? 32 : jstart); j >= 1; j >>= 1) {
                        shf(A, iA, j, k); shf(Bv, iB, j, k); shf(C, iC, j, k); shf(D, iD, j, k);
                    }
                }
                skey[iA] = A; skey[iB] = Bv; skey[iC] = C; skey[iD] = D;
            }
        } else {
            // ---- exact degenerate fallback: full in-LDS bitonic ----
            #pragma unroll
            for (int t = 0; t < 4; ++t) skey[tid + t * 512] = kreg[t];
            __syncthreads();
            for (int k = 2; k <= NB; k <<= 1)
                for (int j = k >> 1; j > 0; j >>= 1) {
                    for (int pp = tid; pp < (NB >> 1); pp += 512) {
                        int i1 = ((pp & ~(j - 1)) << 1) | (pp & (j - 1));
                        int i2 = i1 + j;
                        bool up = ((i1 & k) == 0);
                        u64 a = skey[i1], c2 = skey[i2];
                        if (up ? (a < c2) : (a > c2)) { skey[i1] = c2; skey[i2] = a; }
                    }
                    __syncthreads();
                }
        }
        __syncthreads();

        // ---- output ----
        float* boxes_out   = out + (size_t)b * MAX_DET * 4;
        float* scores_out  = out + (size_t)B * MAX_DET * 4 + (size_t)b * MAX_DET;
        float* classes_out = out + (size_t)B * MAX_DET * 5 + (size_t)b * MAX_DET;
        float* numdet_out  = out + (size_t)B * MAX_DET * 6 + b;

        int nd = keptT < MAX_DET ? keptT : MAX_DET;
        if (tid < MAX_DET) {
            if (tid < nd) {
                u64 kk = skey[tid];
                int orig = (int)(u32)kk;
                const float* q = P + orig * 6;
                boxes_out[tid * 4 + 0] = q[0];
                boxes_out[tid * 4 + 1] = q[1];
                boxes_out[tid * 4 + 2] = q[2];
                boxes_out[tid * 4 + 3] = q[3];
                scores_out[tid]  = __uint_as_float((u32)(kk >> 32));
                classes_out[tid] = q[4];
            } else {
                boxes_out[tid * 4 + 0] = 0.f;
                boxes_out[tid * 4 + 1] = 0.f;
                boxes_out[tid * 4 + 2] = 0.f;
                boxes_out[tid * 4 + 3] = 0.f;
                scores_out[tid]  = 0.f;
                classes_out[tid] = 0.f;
            }
        }
        if (tid == 0) *numdet_out = (float)nd;
    }
}

// ====================================================================
// Fallback (round-0 monolithic, validated) for unexpected shapes/ws.
// ====================================================================
__global__ __launch_bounds__(1024) void nms_fallback(const float* __restrict__ pred,
                                                     float* __restrict__ out, int B) {
    const int b = blockIdx.x, tid = threadIdx.x;
    __shared__ u64 keys[NB];
    __shared__ float bx1[NB], by1[NB], bx2[NB], by2[NB];
    __shared__ int kc[NB];
    __shared__ int cnt[NCLASSES];
    __shared__ int overflow;
    const float* P = pred + (size_t)b * NB * 6;
    for (int i = tid; i < NB; i += 1024) {
        float s = P[i * 6 + 5];
        keys[i] = (s > CONF_T) ? (((u64)__float_as_uint(s) << 32) | (uint32_t)i)
                               : (u64)(uint32_t)i;
    }
    __syncthreads();
    for (int k = 2; k <= NB; k <<= 1)
        for (int j = k >> 1; j > 0; j >>= 1) {
            for (int i = tid; i < NB; i += 1024) {
                int ixj = i ^ j;
                if (ixj > i) {
                    u64 a = keys[i], c = keys[ixj];
                    bool up = ((i & k) == 0);
                    if (up ? (a < c) : (a > c)) { keys[i] = c; keys[ixj] = a; }
                }
            }
            __syncthreads();
        }
    for (int i = tid; i < NB; i += 1024) {
        u64 k = keys[i];
        int orig = (int)(uint32_t)k;
        const float* q = P + orig * 6;
        bx1[i] = q[0]; by1[i] = q[1]; bx2[i] = q[2]; by2[i] = q[3];
        kc[i] = ((k >> 32) != 0) ? (int)q[4] : -1;
    }
    __syncthreads();
    bool dirty = false;
    for (int i = 0; i < NB - 1; ++i) {
        if (i == 0 || dirty) { __syncthreads(); dirty = false; }
        int ci = kc[i];
        if (ci < 0) continue;
        dirty = true;
        float x1i = bx1[i], y1i = by1[i], x2i = bx2[i], y2i = by2[i];
        float ai = fmaxf(x2i - x1i, 0.f) * fmaxf(y2i - y1i, 0.f);
        for (int j = i + 1 + tid; j < NB; j += 1024) {
            if (kc[j] != ci) continue;
            float ix1 = fmaxf(x1i, bx1[j]), iy1 = fmaxf(y1i, by1[j]);
            float ix2 = fminf(x2i, bx2[j]), iy2 = fminf(y2i, by2[j]);
            float inter = fmaxf(ix2 - ix1, 0.f) * fmaxf(iy2 - iy1, 0.f);
            float aj = fmaxf(bx2[j] - bx1[j], 0.f) * fmaxf(by2[j] - by1[j], 0.f);
            if (inter / fmaxf(ai + aj - inter, 1e-8f) > IOU_T) kc[j] = -1;
        }
    }
    __syncthreads();
    for (int i = tid; i < NCLASSES; i += 1024) cnt[i] = 0;
    if (tid == 0) overflow = 0;
    __syncthreads();
    for (int i = tid; i < NB; i += 1024) if (kc[i] >= 0) atomicAdd(&cnt[kc[i]], 1);
    __syncthreads();
    if (tid < NCLASSES && cnt[tid] > MAX_PER_CLASS) atomicOr(&overflow, 1);
    __syncthreads();
    if (overflow) {
        if (tid == 0) {
            for (int c = 0; c < NCLASSES; ++c) cnt[c] = 0;
            for (int i = 0; i < NB; ++i)
                if (kc[i] >= 0 && ++cnt[kc[i]] > MAX_PER_CLASS) kc[i] = -1;
        }
        __syncthreads();
    }
    if (tid < 64) {
        const int lane = tid;
        float* boxes_out   = out + (size_t)b * MAX_DET * 4;
        float* scores_out  = out + (size_t)B * MAX_DET * 4 + (size_t)b * MAX_DET;
        float* classes_out = out + (size_t)B * MAX_DET * 5 + (size_t)b * MAX_DET;
        float* numdet_out  = out + (size_t)B * MAX_DET * 6 + b;
        int running = 0;
        for (int chunk = 0; chunk < NB / 64; ++chunk) {
            int j = chunk * 64 + lane;
            int c = kc[j];
            bool k = (c >= 0);
            u64 m = __ballot(k);
            int pos = running + __popcll(m & ((1ull << lane) - 1ull));
            if (k && pos < MAX_DET) {
                boxes_out[pos * 4 + 0] = bx1[j];
                boxes_out[pos * 4 + 1] = by1[j];
                boxes_out[pos * 4 + 2] = bx2[j];
                boxes_out[pos * 4 + 3] = by2[j];
                scores_out[pos]  = __uint_as_float((uint32_t)(keys[j] >> 32));
                classes_out[pos] = (float)c;
            }
            running += __popcll(m);
        }
        int nd = running < MAX_DET ? running : MAX_DET;
        for (int p = nd + lane; p < MAX_DET; p += 64) {
            boxes_out[p * 4 + 0] = 0.f; boxes_out[p * 4 + 1] = 0.f;
            boxes_out[p * 4 + 2] = 0.f; boxes_out[p * 4 + 3] = 0.f;
            scores_out[p] = 0.f; classes_out[p] = 0.f;
        }
        if (lane == 0) *numdet_out = (float)nd;
    }
}

extern "C" void kernel_launch(void* const* d_in, const int* in_sizes, int n_in,
                              void* d_out, int out_size, void* d_ws, size_t ws_size,
                              hipStream_t stream) {
    const float* pred = (const float*)d_in[0];
    float* out = (float*)d_out;
    const int B = in_sizes[0] / (NB * 6);

    u8* supBytes = (u8*)d_ws;                           // B*2048 bytes
    u32* done = (u32*)(supBytes + (size_t)B * NB);      // B u32
    const size_t need = (size_t)B * NB + (size_t)B * 4;

    if (B != 8 || ws_size < need) {
        nms_fallback<<<B, 1024, 0, stream>>>(pred, out, B);
        return;
    }

    hipMemsetAsync(done, 0, (size_t)B * 4, stream);     // 32 B; graph-safe
    nms_single<<<B * 10 + B, 512, 0, stream>>>(pred, supBytes, done, out, B);
}

// Round 16
// 25.932 us; speedup vs baseline: 1.3780x; 1.3780x over previous
//
#include <hip/hip_runtime.h>
#include <stdint.h>

#define NB 2048
#define NCLASSES 80
#define CONF_T 0.05f
#define IOU_T 0.5f
#define MAX_DET 100
#define MAX_PER_CLASS 100

typedef unsigned long long u64;
typedef unsigned int u32;
typedef unsigned char u8;

__device__ __forceinline__ u64 shfl_xor_u64(u64 v, int mask) {
    int lo = (int)(u32)v, hi = (int)(u32)(v >> 32);
    lo = __shfl_xor(lo, mask, 64);
    hi = __shfl_xor(hi, mask, 64);
    return ((u64)(u32)hi << 32) | (u32)lo;
}

// 512-bucket monotone score hash (r14-validated).
__device__ __forceinline__ int sbucket(u32 bits) {
    int b = (int)(bits >> 17) - 0x1E80;
    return b < 0 ? 0 : (b > 511 ? 511 : b);
}

// ====================================================================
// k_work, grid (B*10 + B) x 512, no cross-block sync:
//  blocks 0..B*10-1: class role (r13-validated) + zero-write supBytes
//                    for invalid boxes of own class (=> every byte
//                    written per call; enables byte-sum in k_fin).
//  blocks B*10..   : cand role: histogram top-256-of-valid (r14
//                    machinery) -> wave-0 512-reg-bitonic (r7-validated
//                    network) -> sorted candG + meta{validTot,degen}.
// ====================================================================
__global__ __launch_bounds__(512) void k_work(const float* __restrict__ pred,
                                              u8* __restrict__ supBytes,
                                              u64* __restrict__ candG,
                                              int* __restrict__ meta, int B) {
    const int bid = blockIdx.x, tid = threadIdx.x;
    const int lane = tid & 63, wave = tid >> 6;            // 8 waves

    __shared__ __align__(16) char smem[49152];

    if (bid < B * 10) {
        // ==================== CLASS role (r13-validated) ====================
        float2* csS  = (float2*)smem;                      // 16 KB
        u64*    wkey = (u64*)(smem + 16384);               // 4 KB  [8][64]
        float4* wb4  = (float4*)(smem + 20480);            // 8 KB  [8][64]
        u64*    wm   = (u64*)(smem + 28672);               // 4 KB  [8][64]
        u8*     fst  = (u8*)(smem + 32768);                // 16 KB [8][2048]

        const int b = bid / 10;
        const int c = (bid % 10) * 8 + wave;
        const float* P = pred + (size_t)b * NB * 6;
        u8* sb = supBytes + (size_t)b * NB;

        for (int i = tid; i < NB; i += 512)
            csS[i] = *reinterpret_cast<const float2*>(P + i * 6 + 4);
        __syncthreads();

        u64* wkeyW = wkey + wave * 64;
        float4* wb4W = wb4 + wave * 64;
        u64* wmW = wm + wave * 64;

        int cnt = 0;
        for (int base = 0; base < NB; base += 64) {
            int i = base + lane;
            float2 cs = csS[i];
            bool mine = ((int)cs.x == c);
            bool v = (cs.y > CONF_T) && mine;
            if (mine && !v) sb[i] = 0;          // invalid box of my class
            u64 m = __ballot(v);
            if (v) {
                int pos = cnt + __popcll(m & ((1ull << lane) - 1ull));
                if (pos < 64) {
                    float2 p01 = *reinterpret_cast<const float2*>(P + i * 6);
                    float2 p23 = *reinterpret_cast<const float2*>(P + i * 6 + 2);
                    wkeyW[pos] = ((u64)__float_as_uint(cs.y) << 32) | (u32)i;
                    wb4W[pos] = make_float4(p01.x, p01.y, p23.x, p23.y);
                }
            }
            cnt += __popcll(m);
        }
        __builtin_amdgcn_wave_barrier();

        if (cnt <= 64) {
            u64 mykey = 0ull; int orig = 0;
            float x1 = 0.f, y1 = 0.f, x2 = 0.f, y2 = 0.f, ar = 0.f;
            if (lane < cnt) {
                mykey = wkeyW[lane];
                orig = (int)(u32)mykey;
                float4 bx = wb4W[lane];
                x1 = bx.x; y1 = bx.y; x2 = bx.z; y2 = bx.w;
                ar = fmaxf(x2 - x1, 0.f) * fmaxf(y2 - y1, 0.f);
            }
            u64 mj = 0ull;
            if (lane < cnt) {
                for (int i = 0; i < cnt; ++i) {
                    u64 ki = wkeyW[i];
                    if (ki > mykey) {
                        float4 bi = wb4W[i];
                        float ari = fmaxf(bi.z - bi.x, 0.f) * fmaxf(bi.w - bi.y, 0.f);
                        float ix1 = fmaxf(bi.x, x1), iy1 = fmaxf(bi.y, y1);
                        float ix2 = fminf(bi.z, x2), iy2 = fminf(bi.w, y2);
                        float inter = fmaxf(ix2 - ix1, 0.f) * fmaxf(iy2 - iy1, 0.f);
                        float uni = ari + ar - inter;
                        if (inter / fmaxf(uni, 1e-8f) > IOU_T) mj |= 1ull << i;
                    }
                }
            }
            u64 conf = __ballot(mj != 0ull);
            bool sup = false;
            if (conf != 0ull) {                            // rare; wave-uniform
                u64 srcs = mj;
                #pragma unroll
                for (int d = 1; d < 64; d <<= 1) srcs |= shfl_xor_u64(srcs, d);
                wmW[lane] = mj;
                __builtin_amdgcn_wave_barrier();
                u64 Cset = srcs | conf;
                u64 keptS2 = 0ull, rem = Cset;
                while (rem) {
                    u64 t = rem, bestk = 0ull; int bi = -1;
                    while (t) {
                        int i = __ffsll(t) - 1; t &= t - 1;
                        u64 k = wkeyW[i];
                        if (k > bestk) { bestk = k; bi = i; }
                    }
                    rem &= ~(1ull << bi);
                    if ((wmW[bi] & keptS2) == 0ull) keptS2 |= 1ull << bi;
                }
                sup = (mj & keptS2) != 0ull;
            }
            if (lane < cnt) sb[orig] = sup ? 1 : 0;
        } else {
            // ---- exact LDS-rescan selection-greedy fallback (~never) ----
            volatile u8* vf = fst + wave * NB;
            for (int o = lane; o < NB; o += 64) vf[o] = 0;
            __builtin_amdgcn_wave_barrier();
            int keptCount = 0;
            for (;;) {
                u64 best = 0ull; int bo = -1;
                for (int o = lane; o < NB; o += 64) {
                    if (vf[o]) continue;
                    float2 cs = csS[o];
                    if (cs.y > CONF_T && (int)cs.x == c) {
                        u64 k = ((u64)__float_as_uint(cs.y) << 32) | (u32)o;
                        if (k > best) { best = k; bo = o; }
                    }
                }
                for (int d = 32; d >= 1; d >>= 1) {
                    u64 ob = shfl_xor_u64(best, d);
                    int obo = __shfl_xor(bo, d, 64);
                    if (ob > best) { best = ob; bo = obo; }
                }
                if (best == 0ull) break;
                keptCount++;
                int orig = (int)(u32)best;
                if (lane == 0) {
                    vf[orig] = 1;
                    sb[orig] = (keptCount > MAX_PER_CLASS) ? 1 : 0;
                }
                __builtin_amdgcn_wave_barrier();
                const float* q = P + orig * 6;
                float ax1 = q[0], ay1 = q[1], ax2 = q[2], ay2 = q[3];
                float aar = fmaxf(ax2 - ax1, 0.f) * fmaxf(ay2 - ay1, 0.f);
                for (int o = lane; o < NB; o += 64) {
                    if (vf[o]) continue;
                    float2 cs = csS[o];
                    if (cs.y > CONF_T && (int)cs.x == c) {
                        const float* q2 = P + o * 6;
                        float bx1 = q2[0], by1 = q2[1], bx2 = q2[2], by2 = q2[3];
                        float br = fmaxf(bx2 - bx1, 0.f) * fmaxf(by2 - by1, 0.f);
                        float ix1 = fmaxf(ax1, bx1), iy1 = fmaxf(ay1, by1);
                        float ix2 = fminf(ax2, bx2), iy2 = fminf(ay2, by2);
                        float inter = fmaxf(ix2 - ix1, 0.f) * fmaxf(iy2 - iy1, 0.f);
                        if (inter / fmaxf(aar + br - inter, 1e-8f) > IOU_T) {
                            vf[o] = 2;
                            sb[o] = 1;
                        }
                    }
                }
                __builtin_amdgcn_wave_barrier();
            }
        }
    } else {
        // ==================== CAND role ====================
        int* hist = (int*)smem;                            // 2 KB
        u64* cand = (u64*)(smem + 4096);                   // 4 KB [512]
        __shared__ int candCnt, TS, validT;

        const int b = bid - B * 10;
        const float* P = pred + (size_t)b * NB * 6;

        for (int i = tid; i < 512; i += 512) { hist[i] = 0; cand[i] = 0ull; }
        if (tid == 0) candCnt = 0;
        __syncthreads();

        u64 kreg[4];
        #pragma unroll
        for (int t = 0; t < 4; ++t) {
            int i = tid + t * 512;
            float s = P[i * 6 + 5];
            u64 kk = 0ull;
            if (s > CONF_T) {
                u32 bits = __float_as_uint(s);
                kk = ((u64)bits << 32) | (u32)i;
                atomicAdd(&hist[sbucket(bits)], 1);
            }
            kreg[t] = kk;
        }
        __syncthreads();

        // threshold: max bucket with suffix >= min(256, total)  (r14 machinery)
        if (tid < 64) {
            int h[8], s = 0;
            #pragma unroll
            for (int t = 0; t < 8; ++t) { h[t] = hist[tid * 8 + t]; s += h[t]; }
            int v = s;
            #pragma unroll
            for (int d = 1; d < 64; d <<= 1) {
                int t2 = __shfl_down(v, d, 64);
                if (tid + d < 64) v += t2;
            }
            int total = __shfl(v, 0, 64);
            int target = total < 256 ? total : 256;
            int run = v - s, bestB = -1;
            for (int t = 7; t >= 0; --t) {
                run += h[t];
                if (run >= target && bestB < 0) bestB = tid * 8 + t;
            }
            int T = bestB;
            #pragma unroll
            for (int d = 32; d >= 1; d >>= 1) {
                int o = __shfl_xor(T, d, 64);
                T = o > T ? o : T;
            }
            if (tid == 0) { TS = T; validT = total; }
        }
        __syncthreads();

        const int T = TS;
        #pragma unroll
        for (int t = 0; t < 4; ++t) {
            u64 kk = kreg[t];
            if (kk != 0ull && sbucket((u32)(kk >> 32)) >= T) {
                int pos = atomicAdd(&candCnt, 1);
                if (pos < 512) cand[pos] = kk;
            }
        }
        __syncthreads();

        int cc = candCnt;
        if (cc <= 512) {
            // wave-0 512-elem register bitonic, descending (r7-validated)
            if (tid < 64) {
                const int ln = tid;
                u64 K[8];
                #pragma unroll
                for (int t = 0; t < 8; ++t) K[t] = cand[ln + 64 * t];

                auto loc = [&](u64& X, u64& Y, int ix, int k) {
                    bool up = ((ix & k) == 0);
                    u64 mx = X > Y ? X : Y, mn = X > Y ? Y : X;
                    X = up ? mx : mn; Y = up ? mn : mx;
                };
                auto shf = [&](u64& V, int iv, int j, int k) {
                    u64 p = shfl_xor_u64(V, j);
                    bool low = ((ln & j) == 0);
                    bool up  = ((iv & k) == 0);
                    V = (low == up) ? (V > p ? V : p) : (V < p ? V : p);
                };
                for (int k = 2; k <= 512; k <<= 1) {
                    int jstart = k >> 1;
                    if (jstart >= 256) {
                        loc(K[0], K[4], ln +   0, k);
                        loc(K[1], K[5], ln +  64, k);
                        loc(K[2], K[6], ln + 128, k);
                        loc(K[3], K[7], ln + 192, k);
                    }
                    if (jstart >= 128) {
                        loc(K[0], K[2], ln +   0, k);
                        loc(K[1], K[3], ln +  64, k);
                        loc(K[4], K[6], ln + 256, k);
                        loc(K[5], K[7], ln + 320, k);
                    }
                    if (jstart >= 64) {
                        loc(K[0], K[1], ln +   0, k);
                        loc(K[2], K[3], ln + 128, k);
                        loc(K[4], K[5], ln + 256, k);
                        loc(K[6], K[7], ln + 384, k);
                    }
                    for (int j = (jstart > 32 ? 32 : jstart); j >= 1; j >>= 1) {
                        #pragma unroll
                        for (int t = 0; t < 8; ++t) shf(K[t], ln + 64 * t, j, k);
                    }
                }
                #pragma unroll
                for (int t = 0; t < 8; ++t) candG[(size_t)b * 512 + ln + 64 * t] = K[t];
            }
            if (tid == 0) { meta[b * 2] = validT; meta[b * 2 + 1] = 0; }
        } else {
            if (tid == 0) { meta[b * 2] = validT; meta[b * 2 + 1] = 1; }  // degenerate
        }
    }
}

// ====================================================================
// k_fin (grid B x 256): bitmap + sorted candidates -> nd -> compacted
// output. Exact full-sort fallback if candidates can't cover nd.
// ====================================================================
__global__ __launch_bounds__(256) void k_fin(const float* __restrict__ pred,
                                             const u8* __restrict__ supBytes,
                                             const u64* __restrict__ candG,
                                             const int* __restrict__ meta,
                                             float* __restrict__ out, int B) {
    const int b = blockIdx.x, tid = threadIdx.x;
    const int wave = tid >> 6, lane = tid & 63;
    __shared__ u32 smw[NB / 4];        // 2 KB
    __shared__ u64 candL[512];         // 4 KB
    __shared__ u64 skey[NB];           // 16 KB (compacted out / fallback)
    __shared__ u64 keptM[8];
    __shared__ int kcnt[8], kbase[8];
    __shared__ int supTot;

    const float* P = pred + (size_t)b * NB * 6;
    const u32* sw = (const u32*)(supBytes + (size_t)b * NB);
    if (tid == 0) supTot = 0;
    for (int i = tid; i < NB / 4; i += 256) smw[i] = sw[i];
    for (int i = tid; i < 512; i += 256) candL[i] = candG[(size_t)b * 512 + i];
    __syncthreads();

    int ls = 0;
    for (int i = tid; i < NB / 4; i += 256) ls += __popc(smw[i] & 0x01010101u);
    if (ls) atomicAdd(&supTot, ls);
    __syncthreads();

    const int validT = meta[b * 2];
    const int degen = meta[b * 2 + 1];
    int keptTotal = validT - supTot;
    int nd = keptTotal < MAX_DET ? keptTotal : MAX_DET;

    bool fast = (degen == 0);
    if (fast) {
        // ---- compact kept candidates (r13-validated pattern, 512) ----
        for (int cc = wave; cc < 8; cc += 4) {
            u64 k = candL[cc * 64 + lane];
            int orig = (int)(u32)k;
            bool kp = ((k >> 32) != 0) &&
                      (((smw[orig >> 2] >> ((orig & 3) * 8)) & 0xFFu) == 0u);
            u64 m = __ballot(kp);
            if (lane == 0) { keptM[cc] = m; kcnt[cc] = __popcll(m); }
        }
        __syncthreads();
        if (tid < 8) {
            int s = 0;
            for (int c2 = 0; c2 < tid; ++c2) s += kcnt[c2];
            kbase[tid] = s;
        }
        __syncthreads();
        int keptInCand = kbase[7] + kcnt[7];
        if (keptInCand >= nd) {
            for (int cc = wave; cc < 8; cc += 4) {
                u64 m = keptM[cc];
                bool kp = (m >> lane) & 1ull;
                int pos = kbase[cc] + __popcll(m & ((1ull << lane) - 1ull));
                if (kp) skey[pos] = candL[cc * 64 + lane];
            }
        } else {
            fast = false;                       // uniform (keptInCand uniform)
        }
        __syncthreads();
    }
    if (!fast) {
        // ---- exact fallback: full 2048 in-LDS bitonic (r14-validated) ----
        #pragma unroll
        for (int t = 0; t < 8; ++t) {
            int i = tid + t * 256;
            float s = P[i * 6 + 5];
            bool sup = ((smw[i >> 2] >> ((i & 3) * 8)) & 0xFFu) != 0u;
            skey[i] = (s > CONF_T && !sup)
                        ? (((u64)__float_as_uint(s) << 32) | (u32)i) : 0ull;
        }
        __syncthreads();
        for (int k = 2; k <= NB; k <<= 1)
            for (int j = k >> 1; j > 0; j >>= 1) {
                for (int pp = tid; pp < (NB >> 1); pp += 256) {
                    int i1 = ((pp & ~(j - 1)) << 1) | (pp & (j - 1));
                    int i2 = i1 + j;
                    bool up = ((i1 & k) == 0);
                    u64 a = skey[i1], c2 = skey[i2];
                    if (up ? (a < c2) : (a > c2)) { skey[i1] = c2; skey[i2] = a; }
                }
                __syncthreads();
            }
    }
    __syncthreads();

    // ---- output ----
    float* boxes_out   = out + (size_t)b * MAX_DET * 4;
    float* scores_out  = out + (size_t)B * MAX_DET * 4 + (size_t)b * MAX_DET;
    float* classes_out = out + (size_t)B * MAX_DET * 5 + (size_t)b * MAX_DET;
    float* numdet_out  = out + (size_t)B * MAX_DET * 6 + b;

    if (tid < MAX_DET) {
        if (tid < nd) {
            u64 kk = skey[tid];
            int orig = (int)(u32)kk;
            const float* q = P + orig * 6;
            boxes_out[tid * 4 + 0] = q[0];
            boxes_out[tid * 4 + 1] = q[1];
            boxes_out[tid * 4 + 2] = q[2];
            boxes_out[tid * 4 + 3] = q[3];
            scores_out[tid]  = __uint_as_float((u32)(kk >> 32));
            classes_out[tid] = q[4];
        } else {
            boxes_out[tid * 4 + 0] = 0.f;
            boxes_out[tid * 4 + 1] = 0.f;
            boxes_out[tid * 4 + 2] = 0.f;
            boxes_out[tid * 4 + 3] = 0.f;
            scores_out[tid]  = 0.f;
            classes_out[tid] = 0.f;
        }
    }
    if (tid == 0) *numdet_out = (float)nd;
}

// ====================================================================
// Fallback (round-0 monolithic, validated) for unexpected shapes/ws.
// ====================================================================
__global__ __launch_bounds__(1024) void nms_fallback(const float* __restrict__ pred,
                                                     float* __restrict__ out, int B) {
    const int b = blockIdx.x, tid = threadIdx.x;
    __shared__ u64 keys[NB];
    __shared__ float bx1[NB], by1[NB], bx2[NB], by2[NB];
    __shared__ int kc[NB];
    __shared__ int cnt[NCLASSES];
    __shared__ int overflow;
    const float* P = pred + (size_t)b * NB * 6;
    for (int i = tid; i < NB; i += 1024) {
        float s = P[i * 6 + 5];
        keys[i] = (s > CONF_T) ? (((u64)__float_as_uint(s) << 32) | (uint32_t)i)
                               : (u64)(uint32_t)i;
    }
    __syncthreads();
    for (int k = 2; k <= NB; k <<= 1)
        for (int j = k >> 1; j > 0; j >>= 1) {
            for (int i = tid; i < NB; i += 1024) {
                int ixj = i ^ j;
                if (ixj > i) {
                    u64 a = keys[i], c = keys[ixj];
                    bool up = ((i & k) == 0);
                    if (up ? (a < c) : (a > c)) { keys[i] = c; keys[ixj] = a; }
                }
            }
            __syncthreads();
        }
    for (int i = tid; i < NB; i += 1024) {
        u64 k = keys[i];
        int orig = (int)(uint32_t)k;
        const float* q = P + orig * 6;
        bx1[i] = q[0]; by1[i] = q[1]; bx2[i] = q[2]; by2[i] = q[3];
        kc[i] = ((k >> 32) != 0) ? (int)q[4] : -1;
    }
    __syncthreads();
    bool dirty = false;
    for (int i = 0; i < NB - 1; ++i) {
        if (i == 0 || dirty) { __syncthreads(); dirty = false; }
        int ci = kc[i];
        if (ci < 0) continue;
        dirty = true;
        float x1i = bx1[i], y1i = by1[i], x2i = bx2[i], y2i = by2[i];
        float ai = fmaxf(x2i - x1i, 0.f) * fmaxf(y2i - y1i, 0.f);
        for (int j = i + 1 + tid; j < NB; j += 1024) {
            if (kc[j] != ci) continue;
            float ix1 = fmaxf(x1i, bx1[j]), iy1 = fmaxf(y1i, by1[j]);
            float ix2 = fminf(x2i, bx2[j]), iy2 = fminf(y2i, by2[j]);
            float inter = fmaxf(ix2 - ix1, 0.f) * fmaxf(iy2 - iy1, 0.f);
            float aj = fmaxf(bx2[j] - bx1[j], 0.f) * fmaxf(by2[j] - by1[j], 0.f);
            if (inter / fmaxf(ai + aj - inter, 1e-8f) > IOU_T) kc[j] = -1;
        }
    }
    __syncthreads();
    for (int i = tid; i < NCLASSES; i += 1024) cnt[i] = 0;
    if (tid == 0) overflow = 0;
    __syncthreads();
    for (int i = tid; i < NB; i += 1024) if (kc[i] >= 0) atomicAdd(&cnt[kc[i]], 1);
    __syncthreads();
    if (tid < NCLASSES && cnt[tid] > MAX_PER_CLASS) atomicOr(&overflow, 1);
    __syncthreads();
    if (overflow) {
        if (tid == 0) {
            for (int c = 0; c < NCLASSES; ++c) cnt[c] = 0;
            for (int i = 0; i < NB; ++i)
                if (kc[i] >= 0 && ++cnt[kc[i]] > MAX_PER_CLASS) kc[i] = -1;
        }
        __syncthreads();
    }
    if (tid < 64) {
        const int lane = tid;
        float* boxes_out   = out + (size_t)b * MAX_DET * 4;
        float* scores_out  = out + (size_t)B * MAX_DET * 4 + (size_t)b * MAX_DET;
        float* classes_out = out + (size_t)B * MAX_DET * 5 + (size_t)b * MAX_DET;
        float* numdet_out  = out + (size_t)B * MAX_DET * 6 + b;
        int running = 0;
        for (int chunk = 0; chunk < NB / 64; ++chunk) {
            int j = chunk * 64 + lane;
            int c = kc[j];
            bool k = (c >= 0);
            u64 m = __ballot(k);
            int pos = running + __popcll(m & ((1ull << lane) - 1ull));
            if (k && pos < MAX_DET) {
                boxes_out[pos * 4 + 0] = bx1[j];
                boxes_out[pos * 4 + 1] = by1[j];
                boxes_out[pos * 4 + 2] = bx2[j];
                boxes_out[pos * 4 + 3] = by2[j];
                scores_out[pos]  = __uint_as_float((uint32_t)(keys[j] >> 32));
                classes_out[pos] = (float)c;
            }
            running += __popcll(m);
        }
        int nd = running < MAX_DET ? running : MAX_DET;
        for (int p = nd + lane; p < MAX_DET; p += 64) {
            boxes_out[p * 4 + 0] = 0.f; boxes_out[p * 4 + 1] = 0.f;
            boxes_out[p * 4 + 2] = 0.f; boxes_out[p * 4 + 3] = 0.f;
            scores_out[p] = 0.f; classes_out[p] = 0.f;
        }
        if (lane == 0) *numdet_out = (float)nd;
    }
}

extern "C" void kernel_launch(void* const* d_in, const int* in_sizes, int n_in,
                              void* d_out, int out_size, void* d_ws, size_t ws_size,
                              hipStream_t stream) {
    const float* pred = (const float*)d_in[0];
    float* out = (float*)d_out;
    const int B = in_sizes[0] / (NB * 6);

    u8* supBytes = (u8*)d_ws;                              // B*2048 bytes
    u64* candG = (u64*)(supBytes + (size_t)B * NB);        // B*512 u64
    int* meta = (int*)(candG + (size_t)B * 512);           // B*2 int
    const size_t need = (size_t)B * NB + (size_t)B * 512 * 8 + (size_t)B * 8;

    if (B != 8 || ws_size < need) {
        nms_fallback<<<B, 1024, 0, stream>>>(pred, out, B);
        return;
    }

    k_work<<<B * 10 + B, 512, 0, stream>>>(pred, supBytes, candG, meta, B);
    k_fin<<<B, 256, 0, stream>>>(pred, supBytes, candG, meta, out, B);
}